// Round 4
// baseline (859.386 us; speedup 1.0000x reference)
//
#include <hip/hip_runtime.h>

typedef __attribute__((ext_vector_type(8))) short short8;
typedef __attribute__((ext_vector_type(4))) short short4v;
typedef __attribute__((ext_vector_type(4))) float float4v;

#define N_EDGES 640000
#define WS_VOFF 98304   // short offset of bf16 V rows in workspace

// RNE float -> bf16 (as raw short)
__device__ __forceinline__ short f2bf(float f) {
  union { float f; unsigned u; } a; a.f = f;
  unsigned r = a.u + 0x7FFFu + ((a.u >> 16) & 1u);
  return (short)(r >> 16);
}

__device__ __forceinline__ float fast_tanh(float x) {
  float xc = fminf(fmaxf(x, -15.f), 15.f);
  float e = __expf(2.f * xc);
  return (e - 1.f) * __builtin_amdgcn_rcpf(e + 1.f);
}

// HBM -> LDS direct DMA, 16B per lane, dest = base + lane*16
__device__ __forceinline__ void gload_lds16(const short* g, short* l) {
  __builtin_amdgcn_global_load_lds(
      (const __attribute__((address_space(1))) unsigned int*)g,
      (__attribute__((address_space(3))) unsigned int*)l, 16, 0, 0);
}

// ws layout (shorts): U[0,16384) V[16384,32768) M1[32768,49152)
//                     W1b[49152,65536) W2[65536,81920)
// b1p (f32[128]) at short offset 81920; bf16 V rows at WS_VOFF (row stride 128).

__global__ void prep_cvt(const float* __restrict__ U_w, const float* __restrict__ V_w,
                         const float* __restrict__ W1, const float* __restrict__ W2,
                         short* __restrict__ ws) {
  int i = blockIdx.x * 256 + threadIdx.x;   // 65536 total
  if (i < 16384) {
    ws[i] = f2bf(U_w[i]);
  } else if (i < 32768) {
    ws[i] = f2bf(V_w[i - 16384]);
  } else if (i < 49152) {
    int j = i - 32768;                       // W1b[o][k] = W1[o][128+k]
    ws[i + 16384] = f2bf(W1[(j >> 7) * 256 + 128 + (j & 127)]);
  } else {
    int j = i - 49152;
    ws[i + 16384] = f2bf(W2[j]);
  }
}

// M1 = W1a @ P_w, bf16; b1p = b1 + W1a @ P_b, f32.
__global__ void prep_mm(const float* __restrict__ W1, const float* __restrict__ P_w,
                        const float* __restrict__ P_b, const float* __restrict__ b1,
                        short* __restrict__ ws) {
  int i = blockIdx.x * 256 + threadIdx.x;   // 16384 total
  int o = i >> 7, k = i & 127;
  const float* wrow = W1 + o * 256;
  const float* pcol = P_w + k;
  float a0 = 0.f, a1 = 0.f, a2 = 0.f, a3 = 0.f;
#pragma unroll
  for (int c = 0; c < 128; c += 4) {
    a0 += wrow[c]     * pcol[c * 128];
    a1 += wrow[c + 1] * pcol[(c + 1) * 128];
    a2 += wrow[c + 2] * pcol[(c + 2) * 128];
    a3 += wrow[c + 3] * pcol[(c + 3) * 128];
  }
  ws[32768 + i] = f2bf((a0 + a1) + (a2 + a3));
  if (i < 128) {
    const float* wr = W1 + i * 256;
    float b = b1[i];
    for (int c = 0; c < 128; c++) b += wr[c] * P_b[c];
    ((float*)(ws + 81920))[i] = b;
  }
}

// V (node features) f32 -> bf16, once. 12.8M elements, 8 per thread.
__global__ void prep_vbf(const float* __restrict__ V, short* __restrict__ ws) {
  int i = blockIdx.x * 256 + threadIdx.x;   // 1.6M total
  if (i >= 1600000) return;
  const float4v* p = (const float4v*)V + (size_t)i * 2;
  float4v a = p[0], b = p[1];
  short8 o = {f2bf(a[0]), f2bf(a[1]), f2bf(a[2]), f2bf(a[3]),
              f2bf(b[0]), f2bf(b[1]), f2bf(b[2]), f2bf(b[3])};
  *(short8*)(ws + WS_VOFF + (size_t)i * 8) = o;
}

// Block = 64 edges, 4 waves (2 n-tiles each). LDS: 2 x [64][128] bf16 (32 KB).
// Gather: global_load_lds DMA from pre-converted bf16 V rows; LDS dest is
// linear, global source chunk pre-swizzled with c = slot ^ (row&7); every
// LDS read/write of the tiles applies the same XOR (conflict-free-ish, no pad).
//   bufA: Vsrc -> t -> h1       bufB: Vdst -> Ea
__global__ __launch_bounds__(256, 4) void fused_kernel(
    const float* __restrict__ E,
    const int* __restrict__ src, const int* __restrict__ dst,
    const short* __restrict__ wbf,
    const float* __restrict__ b2, float* __restrict__ out) {
  __shared__ short bufA[64][128];
  __shared__ short bufB[64][128];

  const int tid  = threadIdx.x;
  const int lane = tid & 63;
  const int wave = tid >> 6;
  const int l15  = lane & 15;
  const int quad = lane >> 4;
  const int eb   = blockIdx.x * 64;
  const int n0   = wave * 2;            // this wave's first n-tile

  const short* wU   = wbf;
  const short* wV   = wbf + 16384;
  const short* wM1  = wbf + 32768;
  const short* wW1b = wbf + 49152;
  const short* wW2  = wbf + 65536;
  const float* b1p  = (const float*)(wbf + 81920);
  const short* Vbf  = wbf + WS_VOFF;

  float b1v[2], b2v[2];
#pragma unroll
  for (int n = 0; n < 2; n++) {
    int c = (n0 + n) * 16 + l15;
    b1v[n] = b1p[c]; b2v[n] = b2[c];
  }

  // ---------- gather: DMA bf16 V rows -> LDS (zero data VGPRs) ----------
  {
    const int rb  = wave * 16;       // this wave's 16 rows
    const int sub = lane >> 4;       // row within 4-row DMA group
    const int cs  = lane & 15;       // 16B slot in LDS
#pragma unroll
    for (int i = 0; i < 4; i++) {
      int row = rb + i * 4 + sub;
      int e   = eb + row;
      int si  = src[e];
      int di  = dst[e];
      int ch  = cs ^ (row & 7);                 // pre-swizzled source chunk
      const short* gs = Vbf + (size_t)si * 128 + ch * 8;
      const short* gd = Vbf + (size_t)di * 128 + ch * 8;
      gload_lds16(gs, &bufA[rb + i * 4][0]);
      gload_lds16(gd, &bufB[rb + i * 4][0]);
    }
  }
  // E prefetch into regs (latency merges with gather wait)
  float4v ef[8];
#pragma unroll
  for (int i = 0; i < 8; i++) {
    int idx = tid + (i << 8);
    int row = idx >> 5;
    int ch  = idx & 31;
    ef[i] = __builtin_nontemporal_load(
        (const float4v*)(E + (size_t)(eb + row) * 128) + ch);
  }
  __syncthreads();

  // ---------- stage 1: t = tanh((Vs@U^T)*(Vd@Vw^T)), per-m tiled ----------
  short8 tpk[4];
#pragma unroll
  for (int m = 0; m < 4; m++) {
    float4v accS[2] = {(float4v){0.f,0.f,0.f,0.f}, (float4v){0.f,0.f,0.f,0.f}};
    float4v accD[2] = {(float4v){0.f,0.f,0.f,0.f}, (float4v){0.f,0.f,0.f,0.f}};
#pragma unroll
    for (int kk = 0; kk < 4; kk++) {
      short8 bU[2], bV[2];
#pragma unroll
      for (int n = 0; n < 2; n++) {
        const int off = ((n0 + n) * 16 + l15) * 128 + kk * 32 + quad * 8;
        bU[n] = *(const short8*)(wU + off);
        bV[n] = *(const short8*)(wV + off);
      }
      const int sw = ((kk * 4 + quad) ^ (l15 & 7)) * 8;   // swizzled 16B slot
      short8 aS = *(const short8*)&bufA[m * 16 + l15][sw];
      short8 aD = *(const short8*)&bufB[m * 16 + l15][sw];
#pragma unroll
      for (int n = 0; n < 2; n++) {
        accS[n] = __builtin_amdgcn_mfma_f32_16x16x32_bf16(aS, bU[n], accS[n], 0, 0, 0);
        accD[n] = __builtin_amdgcn_mfma_f32_16x16x32_bf16(aD, bV[n], accD[n], 0, 0, 0);
      }
    }
    short tv[8];
#pragma unroll
    for (int n = 0; n < 2; n++)
#pragma unroll
      for (int r = 0; r < 4; r++)
        tv[n * 4 + r] = f2bf(fast_tanh(accS[n][r] * accD[n][r]));
    tpk[m] = (short8){tv[0], tv[1], tv[2], tv[3], tv[4], tv[5], tv[6], tv[7]};
  }
  __syncthreads();   // stage-1 LDS reads done; bufA, bufB free

  // t -> bufA ; Ea -> bufB (both swizzled writes)
#pragma unroll
  for (int m = 0; m < 4; m++)
#pragma unroll
    for (int n = 0; n < 2; n++)
#pragma unroll
      for (int r = 0; r < 4; r++) {
        int row = m * 16 + quad * 4 + r;
        int col = (n0 + n) * 16 + l15;
        bufA[row][((col >> 3) ^ (row & 7)) * 8 + (col & 7)] = tpk[m][n * 4 + r];
      }
#pragma unroll
  for (int i = 0; i < 8; i++) {
    int idx = tid + (i << 8);
    int row = idx >> 5;
    int ch  = idx & 31;                       // 8B chunk index
    float4v x = ef[i];
    float e0 = x[0] > 0.f ? x[0] : 0.01f * x[0];
    float e1 = x[1] > 0.f ? x[1] : 0.01f * x[1];
    float e2 = x[2] > 0.f ? x[2] : 0.01f * x[2];
    float e3 = x[3] > 0.f ? x[3] : 0.01f * x[3];
    short4v pe = {f2bf(e0), f2bf(e1), f2bf(e2), f2bf(e3)};
    *(short4v*)&bufB[row][((ch >> 1) ^ (row & 7)) * 8 + (ch & 1) * 4] = pe;
  }
  __syncthreads();

  // ---------- stage 3': h1 = relu(t @ M1^T + Ea @ W1b^T + b1') ----------
  float4v accH[4][2];
#pragma unroll
  for (int m = 0; m < 4; m++)
#pragma unroll
    for (int n = 0; n < 2; n++) accH[m][n] = (float4v){0.f, 0.f, 0.f, 0.f};
#pragma unroll
  for (int kk = 0; kk < 4; kk++) {   // K-half A: t @ M1
    short8 bM[2];
#pragma unroll
    for (int n = 0; n < 2; n++)
      bM[n] = *(const short8*)(wM1 + ((n0 + n) * 16 + l15) * 128 + kk * 32 + quad * 8);
    const int sw = ((kk * 4 + quad) ^ (l15 & 7)) * 8;
#pragma unroll
    for (int m = 0; m < 4; m++) {
      short8 a = *(const short8*)&bufA[m * 16 + l15][sw];
#pragma unroll
      for (int n = 0; n < 2; n++)
        accH[m][n] = __builtin_amdgcn_mfma_f32_16x16x32_bf16(a, bM[n], accH[m][n], 0, 0, 0);
    }
  }
#pragma unroll
  for (int kk = 0; kk < 4; kk++) {   // K-half B: Ea @ W1b
    short8 bW[2];
#pragma unroll
    for (int n = 0; n < 2; n++)
      bW[n] = *(const short8*)(wW1b + ((n0 + n) * 16 + l15) * 128 + kk * 32 + quad * 8);
    const int sw = ((kk * 4 + quad) ^ (l15 & 7)) * 8;
#pragma unroll
    for (int m = 0; m < 4; m++) {
      short8 a = *(const short8*)&bufB[m * 16 + l15][sw];
#pragma unroll
      for (int n = 0; n < 2; n++)
        accH[m][n] = __builtin_amdgcn_mfma_f32_16x16x32_bf16(a, bW[n], accH[m][n], 0, 0, 0);
    }
  }
  __syncthreads();   // stage-3' LDS reads done; bufA free

  // h1 -> bufA (swizzled)
#pragma unroll
  for (int m = 0; m < 4; m++)
#pragma unroll
    for (int n = 0; n < 2; n++)
#pragma unroll
      for (int r = 0; r < 4; r++) {
        int row = m * 16 + quad * 4 + r;
        int col = (n0 + n) * 16 + l15;
        float v = fmaxf(accH[m][n][r] + b1v[n], 0.f);
        bufA[row][((col >> 3) ^ (row & 7)) * 8 + (col & 7)] = f2bf(v);
      }
  __syncthreads();

  // ---------- stage 4: out = relu(h1 @ W2^T + b2) -> global ----------
  {
    float4v accO[4][2];
#pragma unroll
    for (int m = 0; m < 4; m++)
#pragma unroll
      for (int n = 0; n < 2; n++) accO[m][n] = (float4v){0.f, 0.f, 0.f, 0.f};
#pragma unroll
    for (int kk = 0; kk < 4; kk++) {
      short8 bW[2];
#pragma unroll
      for (int n = 0; n < 2; n++)
        bW[n] = *(const short8*)(wW2 + ((n0 + n) * 16 + l15) * 128 + kk * 32 + quad * 8);
      const int sw = ((kk * 4 + quad) ^ (l15 & 7)) * 8;
#pragma unroll
      for (int m = 0; m < 4; m++) {
        short8 a = *(const short8*)&bufA[m * 16 + l15][sw];
#pragma unroll
        for (int n = 0; n < 2; n++)
          accO[m][n] = __builtin_amdgcn_mfma_f32_16x16x32_bf16(a, bW[n], accO[m][n], 0, 0, 0);
      }
    }
#pragma unroll
    for (int m = 0; m < 4; m++)
#pragma unroll
      for (int n = 0; n < 2; n++)
#pragma unroll
        for (int r = 0; r < 4; r++) {
          float v = fmaxf(accO[m][n][r] + b2v[n], 0.f);
          __builtin_nontemporal_store(
              v, out + (size_t)(eb + m * 16 + quad * 4 + r) * 128 + (n0 + n) * 16 + l15);
        }
  }
}

extern "C" void kernel_launch(void* const* d_in, const int* in_sizes, int n_in,
                              void* d_out, int out_size, void* d_ws, size_t ws_size,
                              hipStream_t stream) {
  const float* V   = (const float*)d_in[0];
  const float* E   = (const float*)d_in[1];
  const int*   src = (const int*)d_in[2];
  const int*   dst = (const int*)d_in[3];
  const float* U_w = (const float*)d_in[4];
  const float* V_w = (const float*)d_in[5];
  const float* P_w = (const float*)d_in[6];
  const float* P_b = (const float*)d_in[7];
  const float* W1  = (const float*)d_in[8];
  const float* b1  = (const float*)d_in[9];
  const float* W2  = (const float*)d_in[10];
  const float* b2  = (const float*)d_in[11];
  short* ws = (short*)d_ws;

  hipLaunchKernelGGL(prep_cvt, dim3(256), dim3(256), 0, stream, U_w, V_w, W1, W2, ws);
  hipLaunchKernelGGL(prep_mm, dim3(64), dim3(256), 0, stream, W1, P_w, P_b, b1, ws);
  hipLaunchKernelGGL(prep_vbf, dim3(6250), dim3(256), 0, stream, V, ws);
  hipLaunchKernelGGL(fused_kernel, dim3(N_EDGES / 64), dim3(256), 0, stream,
                     E, src, dst, ws, b2, (float*)d_out);
}